// Round 14
// baseline (8041.019 us; speedup 1.0000x reference)
//
#include <hip/hip_runtime.h>
#include <hip/hip_bf16.h>
#include <cstdint>
#include <cstddef>

#define BN 8192
#define MTOT 32768   // 4*BN
#define GSZ 512      // persistent grid: 2 blocks/CU x 256 CUs, co-residency guaranteed

using bf16 = __hip_bfloat16;
typedef float f32x4 __attribute__((ext_vector_type(4)));
typedef short short8 __attribute__((ext_vector_type(8)));

__device__ __forceinline__ bf16 f2b(float v) { return __float2bfloat16(v); }
__device__ __forceinline__ float b2f(bf16 v) { return __bfloat162float(v); }
__device__ __forceinline__ float sincos_sum(float x) {          // sin+cos = √2·sin(x+π/4)
    return 1.41421356237f * __sinf(x + 0.78539816340f);
}
__device__ __forceinline__ int imin(int a, int b) { return a < b ? a : b; }
__device__ __forceinline__ int imax(int a, int b) { return a > b ? a : b; }

struct MegaParams {
    const float *x, *cell, *isc;
    const float *c1w, *c1b, *c3w, *c3b, *l5w, *l5b, *l4w, *l4b, *l3w, *l3b, *fw, *fb;
    bf16 *w1d5, *w3d5, *w1d4, *w3d4, *w1d3, *w3d3, *wl5p, *wl4p, *wl3p, *wfp;
    float *bias;
    bf16 *Z4, *Z3, *afin, *Za, *Zb;
    float *outp;
    int nchunk, CM, mt;
};

// ---------------- manual grid barrier (monotonic, two-level, agent scope) --------
__device__ __forceinline__ void gsync(unsigned* cnt1, unsigned* cnt2,
                                      unsigned* gen, int bnum)
{
    __syncthreads();
    if (threadIdx.x == 0) {
        __threadfence();                                    // release my block's writes
        int g = blockIdx.x & 7;                             // 8 groups x 64 blocks
        unsigned o1 = __hip_atomic_fetch_add(&cnt1[g * 32], 1u,
                          __ATOMIC_ACQ_REL, __HIP_MEMORY_SCOPE_AGENT);
        if ((int)o1 == bnum * 64 - 1) {                     // last of my group, this barrier
            unsigned o2 = __hip_atomic_fetch_add(cnt2, 1u,
                              __ATOMIC_ACQ_REL, __HIP_MEMORY_SCOPE_AGENT);
            if ((int)o2 == bnum * 8 - 1)
                __hip_atomic_store(gen, (unsigned)bnum,
                                   __ATOMIC_RELEASE, __HIP_MEMORY_SCOPE_AGENT);
        }
        while ((int)__hip_atomic_load(gen, __ATOMIC_ACQUIRE,
                                      __HIP_MEMORY_SCOPE_AGENT) < bnum)
            __builtin_amdgcn_s_sleep(32);
        __threadfence();                                    // acquire others' writes
    }
    __syncthreads();
}

// ---------------- megabuild element (r11 math) -----------------------------------
template<int WSv>
__device__ __forceinline__ bf16 conv_elem(const float* __restrict__ src, int n, int k)
{
    constexpr int KTRUE = 68 * WSv * WSv;
    float v = 0.f;
    if (n < KTRUE && k < KTRUE) {
        int po = n / 68, oc = n % 68, ro = po / WSv, co = po % WSv;
        int pi = k / 68, ic = k % 68, ri = pi / WSv, ci = pi % WSv;
        int kr = ri - ro + 1, kc = ci - co + 1;
        if (kr >= 0 && kr < 3 && kc >= 0 && kc < 3)
            v = src[((oc * 68 + ic) * 3 + kr) * 3 + kc];
    }
    return f2b(v);
}
template<int WSv>
__device__ __forceinline__ bf16 lin_elem(const float* __restrict__ wl, int n, int k)
{
    constexpr int KTRUE = 68 * WSv * WSv;
    float v = 0.f;
    if (n < 576 && k < KTRUE) {
        int pi = k / 68, ic = k % 68;
        v = wl[(size_t)n * KTRUE + ic * (WSv * WSv) + pi];
    }
    return f2b(v);
}

#define MB_OT (2u*1792*1728 + 2u*1152*1088 + 2u*640*640 + 640u*1728 + 640u*1088 \
             + 640u*640 + 128u*576 + 9216u + 4u*8192*16*4 + 4u*8192*9*4 + 32768u*28)

__device__ void megabuild_elem(unsigned e, const MegaParams& P)
{
    constexpr unsigned S0 = 2u*1792*1728, S1 = 2u*1152*1088, S2 = 2u*640*640;
    constexpr unsigned S3 = 640u*1728, S4 = 640u*1088, S5 = 640u*640;
    constexpr unsigned S6 = 128u*576, S7 = 9216;
    constexpr unsigned S8 = 4u*8192*16*4, S9 = 4u*8192*9*4;
    constexpr unsigned O1=S0, O2=O1+S1, O3=O2+S2, O4=O3+S3, O5=O4+S4, O6=O5+S5,
                       O7=O6+S6, O8=O7+S7, O9=O8+S8, O10=O9+S9;
    if (e < O1) {
        constexpr unsigned per = 1792u*1728;
        unsigned i = (e < per) ? e : e - per;
        bf16* dst = (e < per) ? P.w1d5 : P.w3d5;
        const float* src = (e < per) ? P.c1w : P.c3w;
        dst[i] = conv_elem<5>(src, (int)(i / 1728u), (int)(i % 1728u));
    } else if (e < O2) {
        unsigned i0 = e - O1; constexpr unsigned per = 1152u*1088;
        unsigned i = (i0 < per) ? i0 : i0 - per;
        bf16* dst = (i0 < per) ? P.w1d4 : P.w3d4;
        const float* src = (i0 < per) ? P.c1w : P.c3w;
        dst[i] = conv_elem<4>(src, (int)(i / 1088u), (int)(i % 1088u));
    } else if (e < O3) {
        unsigned i0 = e - O2; constexpr unsigned per = 640u*640;
        unsigned i = (i0 < per) ? i0 : i0 - per;
        bf16* dst = (i0 < per) ? P.w1d3 : P.w3d3;
        const float* src = (i0 < per) ? P.c1w : P.c3w;
        dst[i] = conv_elem<3>(src, (int)(i / 640u), (int)(i % 640u));
    } else if (e < O4) {
        unsigned i = e - O3;
        P.wl5p[i] = lin_elem<5>(P.l5w, (int)(i / 1728u), (int)(i % 1728u));
    } else if (e < O5) {
        unsigned i = e - O4;
        P.wl4p[i] = lin_elem<4>(P.l4w, (int)(i / 1088u), (int)(i % 1088u));
    } else if (e < O6) {
        unsigned i = e - O5;
        P.wl3p[i] = lin_elem<3>(P.l3w, (int)(i / 640u), (int)(i % 640u));
    } else if (e < O7) {
        unsigned i = e - O6, n = i / 576u, k = i % 576u;
        P.wfp[i] = (n < 64u) ? f2b(P.fw[n * 576u + k]) : f2b(0.f);
    } else if (e < O8) {
        int i = (int)(e - O7);
        float v = 0.f;
        if (i < 1792)      { int n = i;        if (n < 1700) v = P.c1b[n % 68]; }
        else if (i < 3584) { int n = i - 1792; if (n < 1700) v = P.c3b[n % 68]; }
        else if (i < 4736) { int n = i - 3584; if (n < 1088) v = P.c1b[n % 68]; }
        else if (i < 5888) { int n = i - 4736; if (n < 1088) v = P.c3b[n % 68]; }
        else if (i < 6528) { int n = i - 5888; if (n < 612)  v = P.c1b[n % 68]; }
        else if (i < 7168) { int n = i - 6528; if (n < 612)  v = P.c3b[n % 68]; }
        else if (i < 7808) { int n = i - 7168; if (n < 576)  v = P.l5b[n]; }
        else if (i < 8448) { int n = i - 7808; if (n < 576)  v = P.l4b[n]; }
        else if (i < 9088) { int n = i - 8448; if (n < 576)  v = P.l3b[n]; }
        else               { int n = i - 9088; if (n < 64)   v = P.fb[n]; }
        P.bias[i] = v;
    } else if (e < O9) {
        unsigned i = e - O8;
        int j = (int)(i & 3u); i >>= 2;
        int pi = (int)(i & 15u); i >>= 4;
        int b = (int)(i & 8191u); int q = (int)(i >> 13);
        float t;
        if (j < 2) t = P.cell[b * 2 + j];
        else {
            int r = (q >> 1) * 2 + pi / 4, c = (q & 1) * 2 + pi % 4;
            t = P.isc[((size_t)b * 2 + (j - 2)) * 36 + r * 6 + c];
        }
        P.Z4[((size_t)q * BN + b) * 1088 + pi * 68 + 64 + j] = f2b(sincos_sum(t));
    } else if (e < O10) {
        unsigned i = e - O9;
        int j = (int)(i & 3u); i >>= 2;
        int pi = (int)(i % 9u); i /= 9u;
        int b = (int)(i & 8191u); int q = (int)(i >> 13);
        float t;
        if (j < 2) t = P.cell[b * 2 + j];
        else {
            int r = (q >> 1) * 3 + pi / 3, c = (q & 1) * 3 + pi % 3;
            t = P.isc[((size_t)b * 2 + (j - 2)) * 36 + r * 6 + c];
        }
        P.Z3[((size_t)q * BN + b) * 640 + pi * 68 + 64 + j] = f2b(sincos_sum(t));
    } else {
        unsigned i = e - O10;
        int m = (int)(i / 28u), t = (int)(i % 28u);
        P.Z3[(size_t)m * 640 + 612 + t] = f2b(0.f);
    }
}

// ---------------- zprep for one batch element (r11 math) -------------------------
__device__ void zprep_b(int b, const MegaParams& P, int m0g, bf16* smem)
{
    constexpr int KD = 1728, KTRUE = 1700;
    const int tid = threadIdx.x;
    float (*s)[37] = (float(*)[37])smem;   // 68*37*4 = 10064 B <= 16 KB

    for (int i = tid; i < 64 * 36; i += 256) {
        int ic = i / 36, off = i % 36;
        s[ic][off] = sincos_sum(P.x[((size_t)b * 64 + ic) * 36 + off]);
    }
    if (tid < 2) {
        float t = sincos_sum(P.cell[b * 2 + tid]);
        #pragma unroll
        for (int off = 0; off < 36; off++) s[64 + tid][off] = t;
    }
    if (tid >= 64 && tid < 136) {
        int j = tid - 64;
        int ic = j / 36, off = j % 36;
        s[66 + ic][off] = sincos_sum(P.isc[((size_t)b * 2 + ic) * 36 + off]);
    }
    __syncthreads();

    for (int i = tid; i < 4 * KD; i += 256) {
        int q = i / KD, k = i % KD;
        int gm = q * BN + b;
        if (gm >= m0g && gm < m0g + P.CM) {
            float v = 0.f;
            if (k < KTRUE) {
                int pi = k / 68, ic = k % 68;
                int r = (q >> 1) + pi / 5;
                int c = (q & 1) + pi % 5;
                v = s[ic][r * 6 + c];
            }
            P.Za[(size_t)(gm - m0g) * KD + k] = f2b(v);
        }
    }
    __syncthreads();
}

// ---------------- async global->LDS, 16B per lane --------------------------------
__device__ __forceinline__ void gload_lds16(const bf16* g, const bf16* lds_wave_base)
{
    unsigned off = (unsigned)(uintptr_t)lds_wave_base;
    off = __builtin_amdgcn_readfirstlane(off);
    __builtin_amdgcn_global_load_lds((const __attribute__((address_space(1))) unsigned int*)g,
                                     (__attribute__((address_space(3))) unsigned int*)off,
                                     16, 0, 0);
}

// ---------------- GEMM tile (r11 core + epilogues, r12 smem layout) --------------
template<int EPI, int WS, int WN>
__device__ void gemm_tile(int tileid, int ntiles,
                          const bf16* __restrict__ A, const bf16* __restrict__ Bm, int KD,
                          const float* __restrict__ bias,
                          bf16* __restrict__ C, int ldc, int nlimit,
                          int m0g, bf16* __restrict__ znext,
                          const bf16* __restrict__ afin_xc, float* __restrict__ outp,
                          bf16* smem)
{
    const int tid = threadIdx.x;
    const int wave = tid >> 6, lane = tid & 63;
    const int l15 = lane & 15, lq = lane >> 4;
    const int wr = (wave >> 1) * 64, wc = (wave & 1) * 64;
    const int n_idx = tileid % ntiles, m_idx = tileid / ntiles;
    const int n0 = n_idx * 128, m0 = m_idx * 128;

    int nspans = 1, sbeg[4], send[4];
    sbeg[0] = 0; send[0] = KD;
    if (WS > 0) {
        int po_lo = imin(n0 / 68, WS * WS - 1);
        int po_hi = imin((n0 + 127) / 68, WS * WS - 1);
        int ro_lo = po_lo / WS, ro_hi = po_hi / WS;
        int r_lo = imax(ro_lo - 1, 0), r_hi = imin(ro_hi + 1, WS - 1);
        int ci_lo = 0, ci_hi = WS - 1;
        if (ro_lo == ro_hi) {
            ci_lo = imax(po_lo % WS - 1, 0);
            ci_hi = imin(po_hi % WS + 1, WS - 1);
        }
        if (ci_lo == 0 && ci_hi == WS - 1) {
            sbeg[0] = (r_lo * WS * 68) & ~31;
            send[0] = imin(KD, ((r_hi + 1) * WS * 68 + 31) & ~31);
        } else {
            nspans = 0;
            for (int ri = r_lo; ri <= r_hi; ri++) {
                sbeg[nspans] = ((ri * WS + ci_lo) * 68) & ~31;
                send[nspans] = imin(KD, (((ri * WS + ci_hi + 1) * 68) + 31) & ~31);
                nspans++;
            }
        }
    }

    float bj[4];
    #pragma unroll
    for (int j = 0; j < 4; j++) bj[j] = bias[n0 + wc + j * 16 + l15];

    const bf16* Ab = A + (size_t)m0 * KD;
    const bf16* Bb = Bm + (size_t)n0 * KD;
    const int srow = tid >> 2, scol = (tid & 3) * 8;
    const bf16* aG0 = Ab + (size_t)srow * KD + scol;
    const bf16* aG1 = Ab + (size_t)(srow + 64) * KD + scol;
    const bf16* bG0 = Bb + (size_t)srow * KD + scol;
    const bf16* bG1 = Bb + (size_t)(srow + 64) * KD + scol;
    const bf16* lA0 = &smem[wave * 512];
    const bf16* lA1 = &smem[2048 + wave * 512];
    const bf16* lB0 = &smem[4096 + wave * 512];
    const bf16* lB1 = &smem[4096 + 2048 + wave * 512];

    f32x4 acc[4][4];
    #pragma unroll
    for (int i = 0; i < 4; i++)
        #pragma unroll
        for (int j = 0; j < 4; j++) { f32x4 z = {0.f, 0.f, 0.f, 0.f}; acc[i][j] = z; }

    for (int s = 0; s < nspans; s++) {
        for (int k0 = sbeg[s]; k0 < send[s]; k0 += 32) {
            gload_lds16(aG0 + k0, lA0);
            gload_lds16(aG1 + k0, lA1);
            gload_lds16(bG0 + k0, lB0);
            gload_lds16(bG1 + k0, lB1);
            __syncthreads();
            short8 af[4], bg[4];
            #pragma unroll
            for (int i = 0; i < 4; i++) af[i] = *(const short8*)&smem[(wr + i * 16 + l15) * 32 + lq * 8];
            #pragma unroll
            for (int j = 0; j < 4; j++) bg[j] = *(const short8*)&smem[4096 + (wc + j * 16 + l15) * 32 + lq * 8];
            #pragma unroll
            for (int i = 0; i < 4; i++)
                #pragma unroll
                for (int j = 0; j < 4; j++)
                    acc[i][j] = __builtin_amdgcn_mfma_f32_16x16x32_bf16(af[i], bg[j], acc[i][j], 0, 0, 0);
            __syncthreads();
        }
    }

    #pragma unroll
    for (int i = 0; i < 4; i++) {
        #pragma unroll
        for (int j = 0; j < 4; j++) {
            int n = n0 + wc + j * 16 + l15;
            #pragma unroll
            for (int r = 0; r < 4; r++) {
                int m = m0 + wr + i * 16 + lq * 4 + r;
                float v = acc[i][j][r];
                if (EPI == 0) {
                    if (n < nlimit) {
                        v += bj[j]; v = fmaxf(v, 0.f); v = sincos_sum(v);
                        C[(size_t)m * ldc + n] = f2b(v);
                    }
                } else if (EPI == 1) {
                    if (n < nlimit) {
                        v += bj[j]; v = fmaxf(v, 0.f);
                        C[(size_t)m * ldc + n] = f2b(v);
                    }
                } else if (EPI == 2) {
                    if (n < 576) {
                        v += bj[j]; v = fmaxf(v, 0.f);
                        bf16 t = f2b(sincos_sum(v));
                        int gm = m0g + m;
                        int q = gm >> 13, b = gm & (BN - 1);
                        int ch = n / 9, p = n % 9;
                        int R = p / 3 + (q >> 1) * 3, Cc = p % 3 + (q & 1) * 3;
                        constexpr int OFF = 6 - WN;
                        constexpr int KDN = (WN == 4) ? 1088 : 640;
                        #pragma unroll
                        for (int qr = 0; qr < 2; qr++) {
                            int rr = R - OFF * qr;
                            if (rr < 0 || rr >= WN) continue;
                            #pragma unroll
                            for (int qc = 0; qc < 2; qc++) {
                                int cc = Cc - OFF * qc;
                                if (cc < 0 || cc >= WN) continue;
                                int pi = rr * WN + cc;
                                znext[((size_t)((qr * 2 + qc) * BN + b)) * KDN + pi * 68 + ch] = t;
                            }
                        }
                    }
                } else {
                    if (n < 64) {
                        v += bj[j];
                        int gm = m0g + m;
                        int f = gm * 64 + n;
                        int b2 = f >> 8, rem = f & 255;
                        int ch2 = rem >> 2, ii = (rem >> 1) & 1, jj = rem & 1;
                        int qq = ii * 2 + jj;
                        const int offt[4] = {8, 6, 2, 0};
                        float xc = b2f(afin_xc[((size_t)qq * BN + b2) * 576 + ch2 * 9 + offt[qq]]);
                        outp[f] = v * xc;
                    }
                }
            }
        }
    }
    __syncthreads();
}

// ---------------- the fused persistent kernel ------------------------------------
__global__ void __launch_bounds__(256, 2)
mega(MegaParams P, unsigned* cnt1, unsigned* cnt2, unsigned* gen)
{
    __shared__ bf16 smem[8192];
    const int bid = (int)blockIdx.x;
    int bn = 0;

    for (unsigned e = (unsigned)bid * 256u + threadIdx.x; e < MB_OT; e += GSZ * 256u)
        megabuild_elem(e, P);
    gsync(cnt1, cnt2, gen, ++bn);

    // ws=5
    for (int c = 0; c < P.nchunk; c++) {
        int m0g = c * P.CM;
        { int ch = (BN + GSZ - 1) / GSZ, t1 = imin(bid * ch + ch, BN);
          for (int b = bid * ch; b < t1; b++) zprep_b(b, P, m0g, smem); }
        gsync(cnt1, cnt2, gen, ++bn);
        { int T = 14 * P.mt, ch = (T + GSZ - 1) / GSZ, t1 = imin(bid * ch + ch, T);
          for (int t = bid * ch; t < t1; t++)
              gemm_tile<0, 5, 0>(t, 14, P.Za, P.w1d5, 1728, P.bias + 0,
                                 P.Zb, 1728, 1728, 0, nullptr, nullptr, nullptr, smem); }
        gsync(cnt1, cnt2, gen, ++bn);
        { int T = 14 * P.mt, ch = (T + GSZ - 1) / GSZ, t1 = imin(bid * ch + ch, T);
          for (int t = bid * ch; t < t1; t++)
              gemm_tile<1, 5, 0>(t, 14, P.Zb, P.w3d5, 1728, P.bias + 1792,
                                 P.Za, 1728, 1728, 0, nullptr, nullptr, nullptr, smem); }
        gsync(cnt1, cnt2, gen, ++bn);
        { int T = 5 * P.mt, ch = (T + GSZ - 1) / GSZ, t1 = imin(bid * ch + ch, T);
          for (int t = bid * ch; t < t1; t++)
              gemm_tile<2, 0, 4>(t, 5, P.Za, P.wl5p, 1728, P.bias + 7168,
                                 nullptr, 0, 0, m0g, P.Z4, nullptr, nullptr, smem); }
        gsync(cnt1, cnt2, gen, ++bn);
    }
    // ws=4
    for (int c = 0; c < P.nchunk; c++) {
        int m0g = c * P.CM;
        { int T = 9 * P.mt, ch = (T + GSZ - 1) / GSZ, t1 = imin(bid * ch + ch, T);
          for (int t = bid * ch; t < t1; t++)
              gemm_tile<0, 4, 0>(t, 9, P.Z4 + (size_t)m0g * 1088, P.w1d4, 1088,
                                 P.bias + 3584, P.Zb, 1088, 1088,
                                 0, nullptr, nullptr, nullptr, smem); }
        gsync(cnt1, cnt2, gen, ++bn);
        { int T = 9 * P.mt, ch = (T + GSZ - 1) / GSZ, t1 = imin(bid * ch + ch, T);
          for (int t = bid * ch; t < t1; t++)
              gemm_tile<1, 4, 0>(t, 9, P.Zb, P.w3d4, 1088, P.bias + 4736,
                                 P.Za, 1088, 1088, 0, nullptr, nullptr, nullptr, smem); }
        gsync(cnt1, cnt2, gen, ++bn);
        { int T = 5 * P.mt, ch = (T + GSZ - 1) / GSZ, t1 = imin(bid * ch + ch, T);
          for (int t = bid * ch; t < t1; t++)
              gemm_tile<2, 0, 3>(t, 5, P.Za, P.wl4p, 1088, P.bias + 7808,
                                 nullptr, 0, 0, m0g, P.Z3, nullptr, nullptr, smem); }
        gsync(cnt1, cnt2, gen, ++bn);
    }
    // ws=3
    for (int c = 0; c < P.nchunk; c++) {
        int m0g = c * P.CM;
        { int T = 5 * P.mt, ch = (T + GSZ - 1) / GSZ, t1 = imin(bid * ch + ch, T);
          for (int t = bid * ch; t < t1; t++)
              gemm_tile<0, 3, 0>(t, 5, P.Z3 + (size_t)m0g * 640, P.w1d3, 640,
                                 P.bias + 5888, P.Zb, 640, 640,
                                 0, nullptr, nullptr, nullptr, smem); }
        gsync(cnt1, cnt2, gen, ++bn);
        { int T = 5 * P.mt, ch = (T + GSZ - 1) / GSZ, t1 = imin(bid * ch + ch, T);
          for (int t = bid * ch; t < t1; t++)
              gemm_tile<1, 3, 0>(t, 5, P.Zb, P.w3d3, 640, P.bias + 6528,
                                 P.Za, 640, 640, 0, nullptr, nullptr, nullptr, smem); }
        gsync(cnt1, cnt2, gen, ++bn);
        { int T = 5 * P.mt, ch = (T + GSZ - 1) / GSZ, t1 = imin(bid * ch + ch, T);
          for (int t = bid * ch; t < t1; t++)
              gemm_tile<1, 0, 0>(t, 5, P.Za, P.wl3p, 640, P.bias + 8448,
                                 P.afin + (size_t)m0g * 576, 576, 576,
                                 0, nullptr, nullptr, nullptr, smem); }
        gsync(cnt1, cnt2, gen, ++bn);
    }
    // final
    for (int c = 0; c < P.nchunk; c++) {
        int m0g = c * P.CM;
        int T = P.mt, ch = (T + GSZ - 1) / GSZ, t1 = imin(bid * ch + ch, T);
        for (int t = bid * ch; t < t1; t++)
            gemm_tile<3, 0, 0>(t, 1, P.afin + (size_t)m0g * 576, P.wfp, 576,
                               P.bias + 9088, nullptr, 0, 0, m0g,
                               nullptr, P.afin, P.outp, smem);
    }
}

extern "C" void kernel_launch(void* const* d_in, const int* in_sizes, int n_in,
                              void* d_out, int out_size, void* d_ws, size_t ws_size,
                              hipStream_t stream)
{
    MegaParams P;
    P.x    = (const float*)d_in[0];
    P.cell = (const float*)d_in[1];
    P.isc  = (const float*)d_in[2];
    P.c1w  = (const float*)d_in[3];
    P.c1b  = (const float*)d_in[4];
    P.c3w  = (const float*)d_in[5];
    P.c3b  = (const float*)d_in[6];
    P.l5w  = (const float*)d_in[7];
    P.l5b  = (const float*)d_in[8];
    P.l4w  = (const float*)d_in[9];
    P.l4b  = (const float*)d_in[10];
    P.l3w  = (const float*)d_in[11];
    P.l3b  = (const float*)d_in[12];
    P.fw   = (const float*)d_in[13];
    P.fb   = (const float*)d_in[14];
    P.outp = (float*)d_out;

    char* base = (char*)d_ws;
    size_t cur = 0;
    auto take = [&](size_t bytes) -> char* {
        char* r = base + cur; cur += (bytes + 255) & ~(size_t)255; return r;
    };

    const size_t Z4B = (size_t)MTOT * 1088 * 2;
    const size_t Z3B = (size_t)MTOT * 640 * 2;
    const size_t AFB = (size_t)MTOT * 576 * 2;
    size_t wbytes = 2 * (1792ull * 1728 + 1152ull * 1088 + 640ull * 640) * 2
                  + (640ull * 1728 + 640ull * 1088 + 640ull * 640) * 2
                  + 128ull * 576 * 2 + 9216ull * 4 + 4096 + 64 * 256;
    auto need = [&](int nc) -> size_t {
        return Z4B + Z3B + AFB + wbytes + 2 * ((size_t)(MTOT / nc) * 1728 * 2);
    };
    int nchunk = (ws_size >= need(1)) ? 1 : (ws_size >= need(2)) ? 2
               : (ws_size >= need(4)) ? 4 : (ws_size >= need(8)) ? 8 : 16;

    P.Z4   = (bf16*)take(Z4B);
    P.Z3   = (bf16*)take(Z3B);
    P.afin = (bf16*)take(AFB);
    P.w1d5 = (bf16*)take(1792ull * 1728 * 2);
    P.w3d5 = (bf16*)take(1792ull * 1728 * 2);
    P.w1d4 = (bf16*)take(1152ull * 1088 * 2);
    P.w3d4 = (bf16*)take(1152ull * 1088 * 2);
    P.w1d3 = (bf16*)take(640ull * 640 * 2);
    P.w3d3 = (bf16*)take(640ull * 640 * 2);
    P.wl5p = (bf16*)take(640ull * 1728 * 2);
    P.wl4p = (bf16*)take(640ull * 1088 * 2);
    P.wl3p = (bf16*)take(640ull * 640 * 2);
    P.wfp  = (bf16*)take(128ull * 576 * 2);
    P.bias = (float*)take(9216ull * 4);
    unsigned* bar = (unsigned*)take(4096);     // cnt1[8*32] | cnt2 | gen
    P.nchunk = nchunk;
    P.CM = MTOT / nchunk;
    P.mt = P.CM / 128;
    P.Za = (bf16*)take((size_t)P.CM * 1728 * 2);
    P.Zb = (bf16*)take((size_t)P.CM * 1728 * 2);

    unsigned* cnt1 = bar;            // 8 groups x 32-word stride (128B lines)
    unsigned* cnt2 = bar + 8 * 32;
    unsigned* gen  = bar + 8 * 32 + 32;

    hipMemsetAsync(bar, 0, 4096, stream);
    mega<<<GSZ, 256, 0, stream>>>(P, cnt1, cnt2, gen);
}